// Round 1
// baseline (885.388 us; speedup 1.0000x reference)
//
#include <hip/hip_runtime.h>
#include <stdint.h>

typedef unsigned int u32;

#define THRESH 0.5f
#define DECAY  0.2f

// ---------------------------------------------------------------------------
// Kernel A: LIF SNN scan over [nrows, 256] fp32 rows.
// Row layout: L=256 samples = 32 timesteps x 8 lanes (lane s, step t -> l=t*8+s).
// Outputs: linear-packed spike bits (8 x u32 per row, bit l of row in
// word l>>5, position l&31) and per-row spike mean (count/256).
// One block = 256 threads = 32 rows; thread (rl, s) scans lane s of row rl.
// ---------------------------------------------------------------------------
__global__ __launch_bounds__(256) void snn_kernel(const float* __restrict__ x,
                                                  u32* __restrict__ bits,
                                                  float* __restrict__ rowmean,
                                                  int nrows) {
    __shared__ float lds[32 * 260];   // padded stride 260 (16B-aligned rows)
    __shared__ u32   lanew[32 * 8];

    const int tid = threadIdx.x;
    const int rowbase = blockIdx.x * 32;

    // Coalesced stage: 32 rows * 256 floats = 2048 float4
    const float4* src = (const float4*)(x + (size_t)rowbase * 256);
    #pragma unroll
    for (int k = 0; k < 8; ++k) {
        int f = tid + k * 256;          // float4 index 0..2047
        int r = f >> 6;                 // 64 float4 per row
        int c = (f & 63) << 2;
        float4 v = src[f];
        *((float4*)&lds[r * 260 + c]) = v;
    }
    __syncthreads();

    const int rl = tid >> 3;
    const int s  = tid & 7;
    const float* row = &lds[rl * 260];

    float mem = 0.f, spk = 0.f;
    u32 lw = 0;
    #pragma unroll
    for (int t = 0; t < 32; ++t) {
        float xv = row[t * 8 + s];
        // (1-spk) is exactly 0 or 1 -> contraction-safe, bitwise == reference
        mem = mem * DECAY * (1.f - spk) + xv;
        bool fire = mem > THRESH;
        spk = fire ? 1.f : 0.f;
        lw |= (fire ? 1u : 0u) << t;
    }
    lanew[rl * 8 + s] = lw;

    // spike count per row: reduce over the 8 lanes of this row (contiguous)
    int cnt = __popc(lw);
    cnt += __shfl_xor(cnt, 1);
    cnt += __shfl_xor(cnt, 2);
    cnt += __shfl_xor(cnt, 4);
    __syncthreads();

    const int grow = rowbase + rl;
    if (grow < nrows) {
        if (s == 0) rowmean[grow] = (float)cnt * (1.f / 256.f);
        // recompose linear word j (this thread does j = s):
        // word j bit r = spike(t = 4j + (r>>3), s' = r&7)
        const int j = s;
        u32 wv = 0;
        #pragma unroll
        for (int ss = 0; ss < 8; ++ss) {
            u32 nib = (lanew[rl * 8 + ss] >> (4 * j)) & 0xFu;
            u32 spread = (nib & 1u) | ((nib & 2u) << 7) |
                         ((nib & 4u) << 14) | ((nib & 8u) << 21);
            wv |= spread << ss;
        }
        bits[(size_t)grow * 8 + j] = wv;
    }
}

// ---------------------------------------------------------------------------
// Kernel B: SE block. One wave per batch row b; lane = channel c (0..63).
// g = sigmoid( relu(mean @ w1^T) @ w2^T )
// ---------------------------------------------------------------------------
__global__ __launch_bounds__(256) void se_kernel(const float* __restrict__ means,
                                                 const float* __restrict__ w1, // [4,64]
                                                 const float* __restrict__ w2, // [64,4]
                                                 float* __restrict__ gains,
                                                 int B) {
    const int wave = (blockIdx.x * blockDim.x + threadIdx.x) >> 6;
    const int lane = threadIdx.x & 63;
    if (wave >= B) return;

    const float m = means[wave * 64 + lane];
    float h[4];
    #pragma unroll
    for (int j = 0; j < 4; ++j) {
        float v = m * w1[j * 64 + lane];
        v += __shfl_xor(v, 1);
        v += __shfl_xor(v, 2);
        v += __shfl_xor(v, 4);
        v += __shfl_xor(v, 8);
        v += __shfl_xor(v, 16);
        v += __shfl_xor(v, 32);
        h[j] = fmaxf(v, 0.f);
    }
    float a = h[0] * w2[lane * 4 + 0] + h[1] * w2[lane * 4 + 1] +
              h[2] * w2[lane * 4 + 2] + h[3] * w2[lane * 4 + 3];
    gains[wave * 64 + lane] = 1.f / (1.f + expf(-a));
}

// ---------------------------------------------------------------------------
// Kernel C: conv(65x9, stride 65) + ReLU + maxpool(1,2) for both branches,
// then fc(64->2) + softmax. One block per batch element, thread = out column.
// Conv input stays BINARY: 9-tap window rebuilt via one 64-bit funnel shift;
// SE gain applied once per (h, column): acc[o] += g[h] * (sum_kw W*bit).
// Conv weights are wave-uniform -> scalar loads, no VALU cost.
// ---------------------------------------------------------------------------
__global__ __launch_bounds__(256) void conv_fused_kernel(
        const u32*   __restrict__ ebits,   // [B,64,8]
        const u32*   __restrict__ wbits,   // [B,2,8]
        const float* __restrict__ gains,   // [B,64]
        const float* __restrict__ cw1, const float* __restrict__ cb1,
        const float* __restrict__ cw2, const float* __restrict__ cb2,
        const float* __restrict__ fcw, const float* __restrict__ fcb,
        float* __restrict__ out, int B) {
    __shared__ u32   rb[64 * 8];
    __shared__ u32   wb[16];
    __shared__ float g[64];
    __shared__ float ybuf[32 * 257];   // [p=br*16+o][col], padded stride 257
    __shared__ float yfin[64];

    const int b   = blockIdx.x;
    const int tid = threadIdx.x;

    if (tid < 64) g[tid] = gains[b * 64 + tid];
    if (tid < 16) wb[tid] = wbits[b * 16 + tid];
    rb[tid]       = ebits[(size_t)b * 512 + tid];
    rb[256 + tid] = ebits[(size_t)b * 512 + 256 + tid];
    __syncthreads();

    const int w = tid;
    float acc0[16], acc1[16];
    #pragma unroll
    for (int o = 0; o < 16; ++o) { acc0[o] = 0.f; acc1[o] = 0.f; }

    if (w < 248) {
        const int i0 = w >> 5;
        const int i1 = (w + 8) >> 5;
        const int sh = w & 31;
        float xv[9];

        // h = 0 : wav row (gain = 1), per branch
        {
            u32 nine = (u32)(((((unsigned long long)wb[i1]) << 32) | wb[i0]) >> sh) & 0x1FFu;
            #pragma unroll
            for (int kw = 0; kw < 9; ++kw) xv[kw] = ((nine >> kw) & 1u) ? 1.f : 0.f;
            #pragma unroll
            for (int o = 0; o < 16; ++o) {
                float t = 0.f;
                #pragma unroll
                for (int kw = 0; kw < 9; ++kw) t = fmaf(cw1[o * 585 + kw], xv[kw], t);
                acc0[o] += t;
            }
            u32 nine2 = (u32)(((((unsigned long long)wb[8 + i1]) << 32) | wb[8 + i0]) >> sh) & 0x1FFu;
            #pragma unroll
            for (int kw = 0; kw < 9; ++kw) xv[kw] = ((nine2 >> kw) & 1u) ? 1.f : 0.f;
            #pragma unroll
            for (int o = 0; o < 16; ++o) {
                float t = 0.f;
                #pragma unroll
                for (int kw = 0; kw < 9; ++kw) t = fmaf(cw2[o * 585 + kw], xv[kw], t);
                acc1[o] += t;
            }
        }

        // h = 1..64 : shared EEG rows, scaled by g[h-1]
        for (int h = 1; h <= 64; ++h) {
            const u32* row = &rb[(h - 1) * 8];
            u32 nine = (u32)(((((unsigned long long)row[i1]) << 32) | row[i0]) >> sh) & 0x1FFu;
            #pragma unroll
            for (int kw = 0; kw < 9; ++kw) xv[kw] = ((nine >> kw) & 1u) ? 1.f : 0.f;
            const float gh = g[h - 1];
            #pragma unroll
            for (int o = 0; o < 16; ++o) {
                float t = 0.f;
                #pragma unroll
                for (int kw = 0; kw < 9; ++kw) t = fmaf(cw1[(o * 65 + h) * 9 + kw], xv[kw], t);
                acc0[o] = fmaf(gh, t, acc0[o]);
            }
            #pragma unroll
            for (int o = 0; o < 16; ++o) {
                float t = 0.f;
                #pragma unroll
                for (int kw = 0; kw < 9; ++kw) t = fmaf(cw2[(o * 65 + h) * 9 + kw], xv[kw], t);
                acc1[o] = fmaf(gh, t, acc1[o]);
            }
        }
    }

    // bias + relu -> ybuf  (idle cols write into pad / unread region; relu>=0
    // and max over 124 relu values >= 0, so 0-fill is max-neutral)
    #pragma unroll
    for (int o = 0; o < 16; ++o) {
        float y0 = (w < 248) ? fmaxf(acc0[o] + cb1[o], 0.f) : 0.f;
        float y1 = (w < 248) ? fmaxf(acc1[o] + cb2[o], 0.f) : 0.f;
        ybuf[o * 257 + tid]        = y0;
        ybuf[(16 + o) * 257 + tid] = y1;
    }
    __syncthreads();

    // maxpool: thread q -> (p = q>>1, bin = q&1); y index j == q
    if (tid < 64) {
        const int p = tid >> 1, bin = tid & 1;
        const float* srcy = &ybuf[p * 257 + bin * 124];
        float m = 0.f;
        for (int i = 0; i < 124; ++i) m = fmaxf(m, srcy[i]);
        yfin[tid] = m;
    }
    __syncthreads();

    if (tid == 0) {
        float l0 = fcb[0], l1 = fcb[1];
        for (int j = 0; j < 64; ++j) {
            l0 = fmaf(yfin[j], fcw[j], l0);
            l1 = fmaf(yfin[j], fcw[64 + j], l1);
        }
        float mx = fmaxf(l0, l1);
        float e0 = expf(l0 - mx), e1 = expf(l1 - mx);
        float inv = 1.f / (e0 + e1);
        out[b * 2 + 0] = e0 * inv;
        out[b * 2 + 1] = e1 * inv;
        if (b == 0) out[(size_t)B * 2] = THRESH;   // tuple's second element
    }
}

// ---------------------------------------------------------------------------
extern "C" void kernel_launch(void* const* d_in, const int* in_sizes, int n_in,
                              void* d_out, int out_size, void* d_ws, size_t ws_size,
                              hipStream_t stream) {
    const float* eeg   = (const float*)d_in[0];
    const float* stim  = (const float*)d_in[1];
    const float* se_w1 = (const float*)d_in[2];
    const float* se_w2 = (const float*)d_in[3];
    const float* c1w   = (const float*)d_in[4];
    const float* c1b   = (const float*)d_in[5];
    const float* c2w   = (const float*)d_in[6];
    const float* c2b   = (const float*)d_in[7];
    const float* fcw   = (const float*)d_in[8];
    const float* fcb   = (const float*)d_in[9];
    float* out = (float*)d_out;

    const int B = in_sizes[0] / (64 * 256);   // 2048

    // workspace layout
    char* ws = (char*)d_ws;
    size_t off = 0;
    u32* ebits = (u32*)(ws + off);  off += (size_t)B * 64 * 8 * sizeof(u32);   // 4 MB
    u32* wbits = (u32*)(ws + off);  off += (size_t)B * 2 * 8 * sizeof(u32);    // 128 KB
    float* emeans = (float*)(ws + off); off += (size_t)B * 64 * sizeof(float); // 512 KB
    float* wmeans = (float*)(ws + off); off += (size_t)B * 2 * sizeof(float);  // 16 KB
    float* gains  = (float*)(ws + off); off += (size_t)B * 64 * sizeof(float); // 512 KB
    (void)ws_size; (void)n_in; (void)out_size;

    // SNN scans (eeg rows: B*64; wav rows: B*2)
    snn_kernel<<<(B * 64) / 32, 256, 0, stream>>>(eeg, ebits, emeans, B * 64);
    snn_kernel<<<(B * 2) / 32, 256, 0, stream>>>(stim, wbits, wmeans, B * 2);

    // SE gains (one wave per b)
    se_kernel<<<(B + 3) / 4, 256, 0, stream>>>(emeans, se_w1, se_w2, gains, B);

    // conv + pool + fc + softmax (one block per b)
    conv_fused_kernel<<<B, 256, 0, stream>>>(ebits, wbits, gains,
                                             c1w, c1b, c2w, c2b, fcw, fcb, out, B);
}

// Round 6
// 441.668 us; speedup vs baseline: 2.0046x; 2.0046x over previous
//
#include <hip/hip_runtime.h>
#include <stdint.h>

typedef unsigned int u32;
typedef unsigned long long u64;
typedef float v2f __attribute__((ext_vector_type(2)));

#define THRESH 0.5f
#define DECAY  0.2f

// ---------------------------------------------------------------------------
// Kernel A: LIF SNN scan over [nrows, 256] fp32 rows.
// Row layout: L=256 samples = 32 timesteps x 8 lanes (lane s, step t -> l=t*8+s).
// Outputs: linear-packed spike bits (8 x u32 per row, bit l of row in
// word l>>5, position l&31) and per-row spike mean (count/256).
// One block = 256 threads = 32 rows; thread (rl, s) scans lane s of row rl.
// ---------------------------------------------------------------------------
__global__ __launch_bounds__(256) void snn_kernel(const float* __restrict__ x,
                                                  u32* __restrict__ bits,
                                                  float* __restrict__ rowmean,
                                                  int nrows) {
    __shared__ float lds[32 * 260];   // padded stride 260
    __shared__ u32   lanew[32 * 8];

    const int tid = threadIdx.x;
    const int rowbase = blockIdx.x * 32;

    const float4* src = (const float4*)(x + (size_t)rowbase * 256);
    #pragma unroll
    for (int k = 0; k < 8; ++k) {
        int f = tid + k * 256;
        int r = f >> 6;
        int c = (f & 63) << 2;
        float4 v = src[f];
        *((float4*)&lds[r * 260 + c]) = v;
    }
    __syncthreads();

    const int rl = tid >> 3;
    const int s  = tid & 7;
    const float* row = &lds[rl * 260];

    float mem = 0.f, spk = 0.f;
    u32 lw = 0;
    #pragma unroll
    for (int t = 0; t < 32; ++t) {
        float xv = row[t * 8 + s];
        // (1-spk) is exactly 0 or 1 -> contraction-safe, bitwise == reference
        mem = mem * DECAY * (1.f - spk) + xv;
        bool fire = mem > THRESH;
        spk = fire ? 1.f : 0.f;
        lw |= (fire ? 1u : 0u) << t;
    }
    lanew[rl * 8 + s] = lw;

    int cnt = __popc(lw);
    cnt += __shfl_xor(cnt, 1);
    cnt += __shfl_xor(cnt, 2);
    cnt += __shfl_xor(cnt, 4);
    __syncthreads();

    const int grow = rowbase + rl;
    if (grow < nrows) {
        if (s == 0) rowmean[grow] = (float)cnt * (1.f / 256.f);
        const int j = s;   // linear word j: bit r = spike(t = 4j + (r>>3), s' = r&7)
        u32 wv = 0;
        #pragma unroll
        for (int ss = 0; ss < 8; ++ss) {
            u32 nib = (lanew[rl * 8 + ss] >> (4 * j)) & 0xFu;
            u32 spread = (nib & 1u) | ((nib & 2u) << 7) |
                         ((nib & 4u) << 14) | ((nib & 8u) << 21);
            wv |= spread << ss;
        }
        bits[(size_t)grow * 8 + j] = wv;
    }
}

// ---------------------------------------------------------------------------
// Kernel B: SE block. One wave per batch row; lane = channel (0..63).
// ---------------------------------------------------------------------------
__global__ __launch_bounds__(256) void se_kernel(const float* __restrict__ means,
                                                 const float* __restrict__ w1, // [4,64]
                                                 const float* __restrict__ w2, // [64,4]
                                                 float* __restrict__ gains,
                                                 int B) {
    const int wave = (blockIdx.x * blockDim.x + threadIdx.x) >> 6;
    const int lane = threadIdx.x & 63;
    if (wave >= B) return;

    const float m = means[wave * 64 + lane];
    float h[4];
    #pragma unroll
    for (int j = 0; j < 4; ++j) {
        float v = m * w1[j * 64 + lane];
        v += __shfl_xor(v, 1);
        v += __shfl_xor(v, 2);
        v += __shfl_xor(v, 4);
        v += __shfl_xor(v, 8);
        v += __shfl_xor(v, 16);
        v += __shfl_xor(v, 32);
        h[j] = fmaxf(v, 0.f);
    }
    float a = h[0] * w2[lane * 4 + 0] + h[1] * w2[lane * 4 + 1] +
              h[2] * w2[lane * 4 + 2] + h[3] * w2[lane * 4 + 3];
    gains[wave * 64 + lane] = 1.f / (1.f + expf(-a));
}

// ---------------------------------------------------------------------------
// Kernel P: repack conv weights [o][65][9] -> wrep[(h*9+kw)*32 + br*16 + o]
// so each (h,kw,br) is 16 contiguous floats (64 B -> s_load_dwordx16).
// ---------------------------------------------------------------------------
__global__ __launch_bounds__(256) void repack_kernel(const float* __restrict__ cw1,
                                                     const float* __restrict__ cw2,
                                                     float* __restrict__ wrep) {
    int i = blockIdx.x * 256 + threadIdx.x;     // 65*9*2*16 = 18720
    if (i < 18720) {
        int o   = i & 15;
        int br  = (i >> 4) & 1;
        int kwh = i >> 5;          // h*9 + kw
        int kw  = kwh % 9;
        int h   = kwh / 9;
        const float* src = br ? cw2 : cw1;
        wrep[i] = src[o * 585 + h * 9 + kw];
    }
}

// ---------------------------------------------------------------------------
// Kernel C: conv(65x9,s=65)+ReLU+maxpool(1,2) both branches + fc + softmax.
// Block = batch element, thread = output column. NO divergence in the main
// loop (cols 248..255 compute garbage on padded buffers, masked at the tail)
// so conv weights are wave-uniform -> scalar s_load. Gains folded into the
// binary operand (xg = bit ? g[h] : 0 == the reference's conv input).
// Packed fp32 FMA over o-pairs.
// ---------------------------------------------------------------------------
__global__ __launch_bounds__(256) void conv_fused_kernel(
        const u32*   __restrict__ ebits,   // [B,64,8]
        const u32*   __restrict__ wbits,   // [B,2,8]
        const float* __restrict__ gains,   // [B,64]
        const float* __restrict__ wrep,    // [65*9*32]
        const float* __restrict__ cb1, const float* __restrict__ cb2,
        const float* __restrict__ fcw, const float* __restrict__ fcb,
        float* __restrict__ out, int B) {
    __shared__ u32   rb[520];        // 64 rows x 8 words + zero pad
    __shared__ u32   wb[24];         // 2 rows x 8 words + zero pad
    __shared__ float g[64];
    __shared__ float ybuf[8 * 260];  // one 8-channel chunk of conv output
    __shared__ float pmax[8][64];    // per-(p, 4-col-segment) partial maxes
    __shared__ float yfin[64];

    const int b   = blockIdx.x;
    const int tid = threadIdx.x;

    if (tid < 64) g[tid] = gains[b * 64 + tid];
    if (tid < 16) wb[tid] = wbits[b * 16 + tid];
    else if (tid < 24) wb[tid] = 0u;
    rb[tid]       = ebits[(size_t)b * 512 + tid];
    rb[256 + tid] = ebits[(size_t)b * 512 + 256 + tid];
    if (tid < 8) rb[512 + tid] = 0u;
    __syncthreads();

    const int i0 = tid >> 5;
    const int i1 = (tid + 8) >> 5;
    const int sh = tid & 31;

    v2f acc0[8], acc1[8];
    #pragma unroll
    for (int j = 0; j < 8; ++j) { acc0[j] = (v2f)0.f; acc1[j] = (v2f)0.f; }

    // ---- h = 0 : wav row, per-branch bits, gain 1 ----
    {
        u32 n1 = (u32)((((u64)wb[i1]     << 32) | wb[i0])     >> sh);
        u32 n2 = (u32)((((u64)wb[8 + i1] << 32) | wb[8 + i0]) >> sh);
        #pragma unroll
        for (int kw = 0; kw < 9; ++kw) {
            const v2f* wp = (const v2f*)(wrep + kw * 32);
            float x1 = ((n1 >> kw) & 1u) ? 1.f : 0.f;
            float x2 = ((n2 >> kw) & 1u) ? 1.f : 0.f;
            v2f xv1 = {x1, x1};
            v2f xv2 = {x2, x2};
            #pragma unroll
            for (int j = 0; j < 8; ++j) {
                acc0[j] = __builtin_elementwise_fma(wp[j],     xv1, acc0[j]);
                acc1[j] = __builtin_elementwise_fma(wp[8 + j], xv2, acc1[j]);
            }
        }
    }

    // ---- h = 1..64 : EEG rows, xg = bit ? g[h-1] : 0 ----
    for (int h = 1; h <= 64; ++h) {
        const u32* row = rb + (h - 1) * 8;
        u32 nine = (u32)((((u64)row[i1] << 32) | row[i0]) >> sh);
        const float gh = g[h - 1];
        const float* slab = wrep + h * 288;   // 9 * 32 floats per h
        #pragma unroll
        for (int kw = 0; kw < 9; ++kw) {
            float xs = ((nine >> kw) & 1u) ? gh : 0.f;
            v2f xv = {xs, xs};
            const v2f* wp = (const v2f*)(slab + kw * 32);
            #pragma unroll
            for (int j = 0; j < 8; ++j) {
                acc0[j] = __builtin_elementwise_fma(wp[j],     xv, acc0[j]);
                acc1[j] = __builtin_elementwise_fma(wp[8 + j], xv, acc1[j]);
            }
        }
    }

    // ---- bias + relu, masked to valid cols ----
    float yv[32];
    #pragma unroll
    for (int j = 0; j < 8; ++j) {
        yv[2 * j]          = fmaxf(acc0[j].x + cb1[2 * j],     0.f);
        yv[2 * j + 1]      = fmaxf(acc0[j].y + cb1[2 * j + 1], 0.f);
        yv[16 + 2 * j]     = fmaxf(acc1[j].x + cb2[2 * j],     0.f);
        yv[16 + 2 * j + 1] = fmaxf(acc1[j].y + cb2[2 * j + 1], 0.f);
    }

    // ---- maxpool in 4 chunks of 8 channels (bin0 = cols 0..123, bin1 = 124..247)
    #pragma unroll
    for (int grp = 0; grp < 4; ++grp) {
        #pragma unroll
        for (int pp = 0; pp < 8; ++pp)
            ybuf[pp * 260 + tid] = (tid < 248) ? yv[grp * 8 + pp] : 0.f;
        __syncthreads();
        {
            const int pp = tid >> 5, sl = tid & 31;   // 4-col segments
            float4 a = *(const float4*)&ybuf[pp * 260 + 4 * sl];
            pmax[pp][sl] = fmaxf(fmaxf(a.x, a.y), fmaxf(a.z, a.w));
            if (sl + 32 < 62) {
                float4 c = *(const float4*)&ybuf[pp * 260 + 4 * (sl + 32)];
                pmax[pp][sl + 32] = fmaxf(fmaxf(c.x, c.y), fmaxf(c.z, c.w));
            }
        }
        __syncthreads();
        if (tid < 16) {
            const int pp = tid >> 1, bin = tid & 1;
            const int s0 = bin ? 31 : 0, s1 = bin ? 62 : 31;
            float m = 0.f;
            for (int s = s0; s < s1; ++s) m = fmaxf(m, pmax[pp][s]);
            yfin[(grp * 8 + pp) * 2 + bin] = m;   // y[p*2+bin], p = br*16+o
        }
        __syncthreads();
    }

    if (tid == 0) {
        float l0 = fcb[0], l1 = fcb[1];
        for (int j = 0; j < 64; ++j) {
            float yj = yfin[j];
            l0 = fmaf(yj, fcw[j],      l0);
            l1 = fmaf(yj, fcw[64 + j], l1);
        }
        float mx = fmaxf(l0, l1);
        float e0 = expf(l0 - mx), e1 = expf(l1 - mx);
        float inv = 1.f / (e0 + e1);
        out[b * 2 + 0] = e0 * inv;
        out[b * 2 + 1] = e1 * inv;
        if (b == 0) out[(size_t)B * 2] = THRESH;
    }
}

// ---------------------------------------------------------------------------
extern "C" void kernel_launch(void* const* d_in, const int* in_sizes, int n_in,
                              void* d_out, int out_size, void* d_ws, size_t ws_size,
                              hipStream_t stream) {
    const float* eeg   = (const float*)d_in[0];
    const float* stim  = (const float*)d_in[1];
    const float* se_w1 = (const float*)d_in[2];
    const float* se_w2 = (const float*)d_in[3];
    const float* c1w   = (const float*)d_in[4];
    const float* c1b   = (const float*)d_in[5];
    const float* c2w   = (const float*)d_in[6];
    const float* c2b   = (const float*)d_in[7];
    const float* fcw   = (const float*)d_in[8];
    const float* fcb   = (const float*)d_in[9];
    float* out = (float*)d_out;

    const int B = in_sizes[0] / (64 * 256);   // 2048

    char* ws = (char*)d_ws;
    size_t off = 0;
    u32* ebits = (u32*)(ws + off);  off += (size_t)B * 64 * 8 * sizeof(u32);
    u32* wbits = (u32*)(ws + off);  off += (size_t)B * 2 * 8 * sizeof(u32);
    float* emeans = (float*)(ws + off); off += (size_t)B * 64 * sizeof(float);
    float* wmeans = (float*)(ws + off); off += (size_t)B * 2 * sizeof(float);
    float* gains  = (float*)(ws + off); off += (size_t)B * 64 * sizeof(float);
    float* wrep   = (float*)(ws + off); off += 18720 * sizeof(float);
    (void)ws_size; (void)n_in; (void)out_size;

    repack_kernel<<<74, 256, 0, stream>>>(c1w, c2w, wrep);
    snn_kernel<<<(B * 64) / 32, 256, 0, stream>>>(eeg, ebits, emeans, B * 64);
    snn_kernel<<<(B * 2) / 32, 256, 0, stream>>>(stim, wbits, wmeans, B * 2);
    se_kernel<<<(B + 3) / 4, 256, 0, stream>>>(emeans, se_w1, se_w2, gains, B);
    conv_fused_kernel<<<B, 256, 0, stream>>>(ebits, wbits, gains, wrep,
                                             c1b, c2b, fcw, fcb, out, B);
}

// Round 8
// 288.692 us; speedup vs baseline: 3.0669x; 1.5299x over previous
//
#include <hip/hip_runtime.h>
#include <stdint.h>

typedef unsigned int u32;
typedef unsigned long long u64;
typedef unsigned short u16;
typedef float f32x4 __attribute__((ext_vector_type(4)));
typedef short bf16x8 __attribute__((ext_vector_type(8)));

#define THRESH 0.5f
#define DECAY  0.2f

// RNE f32 -> bf16 (bit trick) and back
__device__ inline u16 f2bf(float v) {
    u32 x = __float_as_uint(v);
    u32 r = x + 0x7FFFu + ((x >> 16) & 1u);
    return (u16)(r >> 16);
}
__device__ inline float bf2f(u16 h) { return __uint_as_float(((u32)h) << 16); }

// ---------------------------------------------------------------------------
// Kernel A: LIF SNN scan, direct global reads (no LDS staging round-trip).
// Row layout: 256 samples = 32 steps x 8 lanes (l = t*8 + s).
// Thread (rl = tid>>3, s = tid&7) scans lane s of row blockIdx*32+rl.
// ---------------------------------------------------------------------------
__global__ __launch_bounds__(256) void snn_kernel(const float* __restrict__ x,
                                                  u32* __restrict__ bits,
                                                  float* __restrict__ rowmean,
                                                  int nrows) {
    __shared__ u32 lanew[32 * 8];
    const int tid = threadIdx.x;
    const int rl = tid >> 3, s = tid & 7;
    const int grow = blockIdx.x * 32 + rl;

    const float* px = x + (size_t)grow * 256 + s;
    float xv[32];
    #pragma unroll
    for (int t = 0; t < 32; ++t) xv[t] = px[t * 8];

    float mem = 0.f, spk = 0.f;
    u32 lw = 0;
    #pragma unroll
    for (int t = 0; t < 32; ++t) {
        // (1-spk) is exactly 0 or 1 -> contraction-safe, bitwise == reference
        mem = mem * DECAY * (1.f - spk) + xv[t];
        bool fire = mem > THRESH;
        spk = fire ? 1.f : 0.f;
        lw |= (fire ? 1u : 0u) << t;
    }
    lanew[rl * 8 + s] = lw;

    int cnt = __popc(lw);
    cnt += __shfl_xor(cnt, 1);
    cnt += __shfl_xor(cnt, 2);
    cnt += __shfl_xor(cnt, 4);
    __syncthreads();

    if (grow < nrows) {
        if (s == 0) rowmean[grow] = (float)cnt * (1.f / 256.f);
        const int j = s;   // linear word j: bit r = spike(t = 4j + (r>>3), s' = r&7)
        u32 wv = 0;
        #pragma unroll
        for (int ss = 0; ss < 8; ++ss) {
            u32 nib = (lanew[rl * 8 + ss] >> (4 * j)) & 0xFu;
            u32 spread = (nib & 1u) | ((nib & 2u) << 7) |
                         ((nib & 4u) << 14) | ((nib & 8u) << 21);
            wv |= spread << ss;
        }
        bits[(size_t)grow * 8 + j] = wv;
    }
}

// ---------------------------------------------------------------------------
// Kernel B: SE block. One wave per batch row; lane = channel (0..63).
// ---------------------------------------------------------------------------
__global__ __launch_bounds__(256) void se_kernel(const float* __restrict__ means,
                                                 const float* __restrict__ w1, // [4,64]
                                                 const float* __restrict__ w2, // [64,4]
                                                 float* __restrict__ gains,
                                                 int B) {
    const int wave = (blockIdx.x * blockDim.x + threadIdx.x) >> 6;
    const int lane = threadIdx.x & 63;
    if (wave >= B) return;

    const float m = means[wave * 64 + lane];
    float h[4];
    #pragma unroll
    for (int j = 0; j < 4; ++j) {
        float v = m * w1[j * 64 + lane];
        v += __shfl_xor(v, 1);
        v += __shfl_xor(v, 2);
        v += __shfl_xor(v, 4);
        v += __shfl_xor(v, 8);
        v += __shfl_xor(v, 16);
        v += __shfl_xor(v, 32);
        h[j] = fmaxf(v, 0.f);
    }
    float a = h[0] * w2[lane * 4 + 0] + h[1] * w2[lane * 4 + 1] +
              h[2] * w2[lane * 4 + 2] + h[3] * w2[lane * 4 + 3];
    gains[wave * 64 + lane] = 1.f / (1.f + expf(-a));
}

// ---------------------------------------------------------------------------
// Kernel C: MFMA conv. Per batch: Y[32][248] = sum_kw A'_kw[32][64] x XT-shift,
// A' = g[h]*W (bf16 hi+lo split, 2 passes), B = raw bits (bf16-exact 0/1).
// Wav row (h=0) added as VALU epilogue. 512 threads = 8 waves x 2 N-tiles.
// MFMA 16x16x32 bf16; frag k-layout chosen contiguous (consistent A/B ->
// correct for any HW k-permutation); A row = lane&15, B col = lane&15,
// D: row=(lane>>4)*4+reg, col=lane&15 (m89-verified).
// ---------------------------------------------------------------------------
__global__ __launch_bounds__(512) void conv_mfma_kernel(
        const u32*   __restrict__ ebits,   // [B,64,8]
        const u32*   __restrict__ wbits,   // [B,2,8]
        const float* __restrict__ gains,   // [B,64]
        const float* __restrict__ cw1, const float* __restrict__ cb1,
        const float* __restrict__ cw2, const float* __restrict__ cb2,
        const float* __restrict__ fcw, const float* __restrict__ fcb,
        float* __restrict__ out, int B) {
    // LDS: XT[272 w][64 h] bf16 (XOR-swz by w&7), A'hi/A'lo[32 o'][9 kw][64 h]
    // bf16 (XOR-swz by o'&7). ybuf[256][36] f32 aliases Alo after GEMM.
    __shared__ __align__(16) char XTbuf[272 * 128];    // 34816
    __shared__ __align__(16) char Ahi[32 * 1152];      // 36864
    __shared__ __align__(16) char Alo[32 * 1152];      // 36864 (ybuf alias)
    __shared__ u32   rb[512];
    __shared__ u32   wb[24];
    __shared__ float gg[64];
    __shared__ float Wh0[288];     // [br][kw][o]
    __shared__ float biasl[32];
    __shared__ float pmax[32][8];
    __shared__ float yfin[64];

    const int b   = blockIdx.x;
    const int tid = threadIdx.x;

    // ---- stage 1: global -> LDS
    rb[tid] = ebits[(size_t)b * 512 + tid];
    if (tid < 16)       wb[tid] = wbits[b * 16 + tid];
    else if (tid < 24)  wb[tid] = 0u;
    if (tid >= 64 && tid < 128)  gg[tid - 64] = gains[b * 64 + (tid - 64)];
    if (tid >= 128 && tid < 416) {
        int idx = tid - 128;                 // 0..287 = br*144 + kw*16 + o
        int br = idx / 144, r = idx % 144;
        int kw = r >> 4, o = r & 15;
        Wh0[idx] = (br ? cw2 : cw1)[o * 585 + kw];
    }
    if (tid >= 416 && tid < 448) {
        int i = tid - 416;
        biasl[i] = (i < 16) ? cb1[i] : cb2[i - 16];
    }
    // zero XT pad rows 256..271 (2048 B)
    ((u32*)(XTbuf + 256 * 128))[tid] = 0u;
    __syncthreads();

    // ---- build XT (bits -> bf16 0/1, swizzled) : thread = (w, h-half)
    {
        const int w = tid >> 1;
        const int half = tid & 1;
        char* rowp = XTbuf + w * 128;
        const u32 sw = (u32)((w & 7) << 4);
        const int c = w >> 5, sh = w & 31;
        #pragma unroll
        for (int q = 0; q < 16; ++q) {
            int hp = half * 16 + q;                    // h-pair index
            u32 b0 = (rb[(2 * hp) * 8 + c] >> sh) & 1u;
            u32 b1 = (rb[(2 * hp + 1) * 8 + c] >> sh) & 1u;
            u32 word = (b0 ? 0x3F80u : 0u) | (b1 ? 0x3F800000u : 0u);
            *(u32*)(rowp + (((u32)(hp * 4)) ^ sw)) = word;
        }
    }

    // ---- build A' hi/lo : thread = (o' 0..31, hgrp 0..15 -> 4 h)
    {
        const int op = tid >> 4;
        const int hgrp = tid & 15;
        const int br = op >> 4, o = op & 15;
        const float* cw = br ? cw2 : cw1;
        const int h0 = hgrp * 4;                       // h_idx base (ref h = 1+h_idx)
        const float* src = cw + o * 585 + (size_t)(1 + h0) * 9;   // 36 consecutive
        float wv[36];
        #pragma unroll
        for (int i = 0; i < 36; ++i) wv[i] = src[i];
        char* rhi = Ahi + op * 1152;
        char* rlo = Alo + op * 1152;
        const u32 sw = (u32)((op & 7) << 4);
        #pragma unroll
        for (int kw = 0; kw < 9; ++kw) {
            u16 hi[4], lo[4];
            #pragma unroll
            for (int j = 0; j < 4; ++j) {
                float v = gg[h0 + j] * wv[j * 9 + kw];
                u16 hb = f2bf(v);
                hi[j] = hb;
                lo[j] = f2bf(v - bf2f(hb));
            }
            u64 ph = (u64)hi[0] | ((u64)hi[1] << 16) | ((u64)hi[2] << 32) | ((u64)hi[3] << 48);
            u64 pl = (u64)lo[0] | ((u64)lo[1] << 16) | ((u64)lo[2] << 32) | ((u64)lo[3] << 48);
            u32 off = ((u32)(kw * 128)) + (((u32)(h0 * 2)) ^ sw);
            *(u64*)(rhi + off) = ph;
            *(u64*)(rlo + off) = pl;
        }
    }
    __syncthreads();

    // ---- main GEMM: wave wv handles N-tiles (wv*2 + nn)
    const int lane15 = tid & 15;
    const int hi4 = (tid >> 4) & 3;
    const int wvid = tid >> 6;

    f32x4 accH[2][2], accL[2][2];
    const f32x4 z4 = {0.f, 0.f, 0.f, 0.f};
    #pragma unroll
    for (int m = 0; m < 2; ++m)
        #pragma unroll
        for (int nn = 0; nn < 2; ++nn) { accH[m][nn] = z4; accL[m][nn] = z4; }

    const u32 sA = (u32)((lane15 & 7) << 4);     // (o'&7)<<4, m*16 == 0 mod 8
    #pragma unroll
    for (int kw = 0; kw < 9; ++kw) {
        #pragma unroll
        for (int ks = 0; ks < 2; ++ks) {
            const u32 kfrag = (u32)(ks * 64 + hi4 * 16);
            bf16x8 faH[2], faL[2];
            #pragma unroll
            for (int m = 0; m < 2; ++m) {
                u32 off = (u32)((m * 16 + lane15) * 1152 + kw * 128) + (kfrag ^ sA);
                faH[m] = *(const bf16x8*)(Ahi + off);
                faL[m] = *(const bf16x8*)(Alo + off);
            }
            #pragma unroll
            for (int nn = 0; nn < 2; ++nn) {
                int wcol = (wvid * 2 + nn) * 16 + lane15 + kw;     // <= 263 < 272
                u32 offb = (u32)(wcol * 128) + (kfrag ^ ((u32)((wcol & 7) << 4)));
                bf16x8 fb = *(const bf16x8*)(XTbuf + offb);
                accH[0][nn] = __builtin_amdgcn_mfma_f32_16x16x32_bf16(faH[0], fb, accH[0][nn], 0, 0, 0);
                accH[1][nn] = __builtin_amdgcn_mfma_f32_16x16x32_bf16(faH[1], fb, accH[1][nn], 0, 0, 0);
                accL[0][nn] = __builtin_amdgcn_mfma_f32_16x16x32_bf16(faL[0], fb, accL[0][nn], 0, 0, 0);
                accL[1][nn] = __builtin_amdgcn_mfma_f32_16x16x32_bf16(faL[1], fb, accL[1][nn], 0, 0, 0);
            }
        }
    }
    __syncthreads();   // A'lo dead; ybuf may now overwrite it

    // ---- epilogue: combine + wav(h=0) + bias + relu -> ybuf[w][36]
    float* ybuf = (float*)Alo;
    #pragma unroll
    for (int nn = 0; nn < 2; ++nn) {
        const int wcol = (wvid * 2 + nn) * 16 + lane15;            // 0..255
        const int i0 = wcol >> 5, i1 = (wcol + 8) >> 5, sh = wcol & 31;
        #pragma unroll
        for (int m = 0; m < 2; ++m) {       // m == branch (rows o' = m*16+o)
            u32 nine = (u32)(((((u64)wb[m * 8 + i1]) << 32) | wb[m * 8 + i0]) >> sh);
            f32x4 y = accH[m][nn] + accL[m][nn];
            #pragma unroll
            for (int kw = 0; kw < 9; ++kw) {
                float xb = ((nine >> kw) & 1u) ? 1.f : 0.f;
                const f32x4 wg = *(const f32x4*)&Wh0[m * 144 + kw * 16 + hi4 * 4];
                y += wg * xb;
            }
            y += *(const f32x4*)&biasl[m * 16 + hi4 * 4];
            y = __builtin_elementwise_max(y, z4);
            *(f32x4*)&ybuf[wcol * 36 + m * 16 + hi4 * 4] = y;
        }
    }
    __syncthreads();

    // ---- maxpool: 256 threads, o' = tid>>3, seg = tid&7 (31 cols each)
    if (tid < 256) {
        const int op = tid >> 3, seg = tid & 7;
        const int w0 = seg * 31;
        float mx = 0.f;
        #pragma unroll
        for (int i = 0; i < 31; ++i) mx = fmaxf(mx, ybuf[(w0 + i) * 36 + op]);
        pmax[op][seg] = mx;
    }
    __syncthreads();
    if (tid < 64) {
        const int p = tid >> 1, bin = tid & 1;
        float mx = fmaxf(fmaxf(pmax[p][bin * 4], pmax[p][bin * 4 + 1]),
                         fmaxf(pmax[p][bin * 4 + 2], pmax[p][bin * 4 + 3]));
        yfin[p * 2 + bin] = mx;    // y[p*2+bin], p = br*16+o (concat order)
    }
    __syncthreads();

    if (tid == 0) {
        float l0 = fcb[0], l1 = fcb[1];
        for (int j = 0; j < 64; ++j) {
            float yj = yfin[j];
            l0 = fmaf(yj, fcw[j],      l0);
            l1 = fmaf(yj, fcw[64 + j], l1);
        }
        float mx = fmaxf(l0, l1);
        float e0 = expf(l0 - mx), e1 = expf(l1 - mx);
        float inv = 1.f / (e0 + e1);
        out[b * 2 + 0] = e0 * inv;
        out[b * 2 + 1] = e1 * inv;
        if (b == 0) out[(size_t)B * 2] = THRESH;
    }
}

// ---------------------------------------------------------------------------
extern "C" void kernel_launch(void* const* d_in, const int* in_sizes, int n_in,
                              void* d_out, int out_size, void* d_ws, size_t ws_size,
                              hipStream_t stream) {
    const float* eeg   = (const float*)d_in[0];
    const float* stim  = (const float*)d_in[1];
    const float* se_w1 = (const float*)d_in[2];
    const float* se_w2 = (const float*)d_in[3];
    const float* c1w   = (const float*)d_in[4];
    const float* c1b   = (const float*)d_in[5];
    const float* c2w   = (const float*)d_in[6];
    const float* c2b   = (const float*)d_in[7];
    const float* fcw   = (const float*)d_in[8];
    const float* fcb   = (const float*)d_in[9];
    float* out = (float*)d_out;

    const int B = in_sizes[0] / (64 * 256);   // 2048

    char* ws = (char*)d_ws;
    size_t off = 0;
    u32* ebits = (u32*)(ws + off);  off += (size_t)B * 64 * 8 * sizeof(u32);
    u32* wbits = (u32*)(ws + off);  off += (size_t)B * 2 * 8 * sizeof(u32);
    float* emeans = (float*)(ws + off); off += (size_t)B * 64 * sizeof(float);
    float* wmeans = (float*)(ws + off); off += (size_t)B * 2 * sizeof(float);
    float* gains  = (float*)(ws + off); off += (size_t)B * 64 * sizeof(float);
    (void)ws_size; (void)n_in; (void)out_size;

    snn_kernel<<<(B * 64) / 32, 256, 0, stream>>>(eeg, ebits, emeans, B * 64);
    snn_kernel<<<(B * 2) / 32, 256, 0, stream>>>(stim, wbits, wmeans, B * 2);
    se_kernel<<<(B + 3) / 4, 256, 0, stream>>>(emeans, se_w1, se_w2, gains, B);
    conv_mfma_kernel<<<B, 512, 0, stream>>>(ebits, wbits, gains,
                                            c1w, c1b, c2w, c2b, fcw, fcb, out, B);
}